// Round 1
// baseline (1096.403 us; speedup 1.0000x reference)
//
#include <hip/hip_runtime.h>
#include <hip/hip_bf16.h>

#define H 64
#define F 128
#define G4 256   // 4*H
#define T 512
#define B 512
#define R 2      // batch rows per block

__device__ __forceinline__ float sigf(float x) {
    return 1.f / (1.f + __expf(-x));
}
__device__ __forceinline__ float tanh_fast(float x) {
    // tanh(x) = 1 - 2/(exp(2x)+1); saturates correctly for |x| large
    float e = __expf(2.f * x);
    return 1.f - 2.f / (e + 1.f);
}

// Fused bidirectional LSTM: each block handles R batch rows of one direction,
// iterating all T timesteps internally (recurrence is batch-independent).
// Thread g owns gate column g; W[:,g] and U[:,g] live in registers.
__global__ __launch_bounds__(256, 2)
void lstm_kernel(const float* __restrict__ x,
                 const float* __restrict__ W_fwd, const float* __restrict__ U_fwd,
                 const float* __restrict__ b_fwd,
                 const float* __restrict__ W_bwd, const float* __restrict__ U_bwd,
                 const float* __restrict__ b_bwd,
                 float* __restrict__ hcat /* [B][2H] */) {
    const int tid  = threadIdx.x;           // gate column g
    const int dir  = blockIdx.x >> 8;       // 0 = fwd, 1 = bwd
    const int rowg = blockIdx.x & 255;      // row group
    const int r0   = rowg * R;

    const float* __restrict__ W = dir ? W_bwd : W_fwd;
    const float* __restrict__ U = dir ? U_bwd : U_fwd;
    const float* __restrict__ bb = dir ? b_bwd : b_fwd;

    // Cache this thread's weight columns in registers.
    float wreg[F];
#pragma unroll
    for (int f = 0; f < F; ++f) wreg[f] = W[f * G4 + tid];
    float ureg[H];
#pragma unroll
    for (int k = 0; k < H; ++k) ureg[k] = U[k * G4 + tid];
    const float bg = bb[tid];

    __shared__ __align__(16) float xs[R][F];
    __shared__ __align__(16) float hs[R][H];
    __shared__ __align__(16) float zb[R][G4];
    __shared__ __align__(16) float cb[R][H];

    if (tid < R * H) {
        int r = tid >> 6, j = tid & 63;
        hs[r][j] = 0.f;
        cb[r][j] = 0.f;
    }
    __syncthreads();

    for (int t = 0; t < T; ++t) {
        const int tt = dir ? (T - 1 - t) : t;

        // Stage x rows for this timestep: R*F = 256 floats, one per thread.
        {
            int r = tid >> 7, f = tid & 127;
            xs[r][f] = x[(size_t)(r0 + r) * T * F + (size_t)tt * F + f];
        }
        __syncthreads();

        // z[r][g] = bias + x.W + h.U  (two partial accumulators to break FMA chains)
        float z0[R], z1[R];
#pragma unroll
        for (int r = 0; r < R; ++r) { z0[r] = bg; z1[r] = 0.f; }

#pragma unroll
        for (int f4 = 0; f4 < F / 4; ++f4) {
#pragma unroll
            for (int r = 0; r < R; ++r) {
                float4 v = ((const float4*)xs[r])[f4];
                z0[r] = fmaf(v.x, wreg[4 * f4 + 0], z0[r]);
                z0[r] = fmaf(v.y, wreg[4 * f4 + 1], z0[r]);
                z1[r] = fmaf(v.z, wreg[4 * f4 + 2], z1[r]);
                z1[r] = fmaf(v.w, wreg[4 * f4 + 3], z1[r]);
            }
        }
#pragma unroll
        for (int k4 = 0; k4 < H / 4; ++k4) {
#pragma unroll
            for (int r = 0; r < R; ++r) {
                float4 v = ((const float4*)hs[r])[k4];
                z0[r] = fmaf(v.x, ureg[4 * k4 + 0], z0[r]);
                z0[r] = fmaf(v.y, ureg[4 * k4 + 1], z0[r]);
                z1[r] = fmaf(v.z, ureg[4 * k4 + 2], z1[r]);
                z1[r] = fmaf(v.w, ureg[4 * k4 + 3], z1[r]);
            }
        }
#pragma unroll
        for (int r = 0; r < R; ++r) zb[r][tid] = z0[r] + z1[r];
        __syncthreads();

        // Gate update: thread (r,j) pairs (first R*H threads).
        if (tid < R * H) {
            int r = tid >> 6, j = tid & 63;
            float zi = zb[r][j];
            float zf = zb[r][H + j];
            float zg = zb[r][2 * H + j];
            float zo = zb[r][3 * H + j];
            float ig = sigf(zi);
            float fg = sigf(zf);
            float gg = tanh_fast(zg);
            float og = sigf(zo);
            float c  = fmaf(fg, cb[r][j], ig * gg);
            cb[r][j] = c;
            hs[r][j] = og * tanh_fast(c);
        }
        __syncthreads();
    }

    // Write final hidden state: fwd -> cols [0,64), bwd -> cols [64,128)
    if (tid < R * H) {
        int r = tid >> 6, j = tid & 63;
        hcat[(size_t)(r0 + r) * (2 * H) + dir * H + j] = hs[r][j];
    }
}

// out[b][e] = relu(sum_k hcat[b][k] * Wd[k][e] + bd[e])
__global__ void dense_kernel(const float* __restrict__ hcat,
                             const float* __restrict__ Wd,
                             const float* __restrict__ bd,
                             float* __restrict__ out) {
    const int b = blockIdx.x;
    const int e = threadIdx.x;   // 128 threads
    float acc = bd[e];
#pragma unroll
    for (int k = 0; k < 2 * H; ++k)
        acc = fmaf(hcat[b * (2 * H) + k], Wd[k * 128 + e], acc);
    out[b * 128 + e] = fmaxf(acc, 0.f);
}

extern "C" void kernel_launch(void* const* d_in, const int* in_sizes, int n_in,
                              void* d_out, int out_size, void* d_ws, size_t ws_size,
                              hipStream_t stream) {
    const float* x      = (const float*)d_in[0];
    const float* W_fwd  = (const float*)d_in[1];
    const float* U_fwd  = (const float*)d_in[2];
    const float* b_fwd  = (const float*)d_in[3];
    const float* W_bwd  = (const float*)d_in[4];
    const float* U_bwd  = (const float*)d_in[5];
    const float* b_bwd  = (const float*)d_in[6];
    const float* W_dense = (const float*)d_in[7];
    const float* b_dense = (const float*)d_in[8];
    float* out = (float*)d_out;

    float* hcat = (float*)d_ws;   // [B][2H] = 256 KB

    // 2 directions * (B/R) row-groups
    lstm_kernel<<<dim3(2 * (B / R)), dim3(256), 0, stream>>>(
        x, W_fwd, U_fwd, b_fwd, W_bwd, U_bwd, b_bwd, hcat);

    dense_kernel<<<dim3(B), dim3(128), 0, stream>>>(hcat, W_dense, b_dense, out);
}

// Round 2
// 519.133 us; speedup vs baseline: 2.1120x; 2.1120x over previous
//
#include <hip/hip_runtime.h>
#include <hip/hip_bf16.h>

#define H 64
#define F 128
#define G4 256   // 4*H
#define T 512
#define B 512
#define RB 16    // batch rows per block

typedef __attribute__((ext_vector_type(4))) float f32x4;
typedef __attribute__((ext_vector_type(8))) short bf16x8;

__device__ __forceinline__ short f2bf(float f) {
    union { float f; unsigned u; } v; v.f = f;
    unsigned r = (v.u + 0x7fffu + ((v.u >> 16) & 1u)) >> 16;
    return (short)r;
}
__device__ __forceinline__ float sigf(float x) {
    return __builtin_amdgcn_rcpf(1.f + __expf(-x));
}
__device__ __forceinline__ float tanhf_(float x) {
    float e = __expf(2.f * x);
    return 1.f - 2.f * __builtin_amdgcn_rcpf(e + 1.f);
}

// Load one timestep's x A-fragments (4 K-tiles of 32) for this lane.
#define LOADX(XR, TT) do {                                                     \
    int _b = (TT) * F + 4 * lq;                                                \
    _Pragma("unroll")                                                          \
    for (int kt = 0; kt < 4; ++kt) {                                           \
        XR[kt][0] = *(const f32x4*)(xlane + _b + 32 * kt);                     \
        XR[kt][1] = *(const f32x4*)(xlane + _b + 32 * kt + 16);                \
    }                                                                          \
} while (0)

// One timestep: convert x, prefetch t+2, h-frag read, 24 MFMAs, in-register
// gates, h-frag write, one barrier.  PRD/PWR = LDS h double-buffer halves.
#define BODY(TCUR, XR, PRD, PWR) do {                                          \
    bf16x8 af[4];                                                              \
    _Pragma("unroll")                                                          \
    for (int kt = 0; kt < 4; ++kt) {                                           \
        bf16x8 v;                                                              \
        _Pragma("unroll")                                                      \
        for (int e = 0; e < 4; ++e) {                                          \
            v[e]     = f2bf(XR[kt][0][e]);                                     \
            v[e + 4] = f2bf(XR[kt][1][e]);                                     \
        }                                                                      \
        af[kt] = v;                                                            \
    }                                                                          \
    {   int tn = (TCUR) + 2; if (tn > T - 1) tn = T - 1;                       \
        int ttn = dir ? (T - 1 - tn) : tn;                                     \
        LOADX(XR, ttn); }                                                      \
    bf16x8 hf0 = *(const bf16x8*)(hlds + (PRD) * 2048 + rd_off);               \
    bf16x8 hf1 = *(const bf16x8*)(hlds + (PRD) * 2048 + 1024 + rd_off);        \
    f32x4 acc[4];                                                              \
    _Pragma("unroll")                                                          \
    for (int s = 0; s < 4; ++s)                                                \
        acc[s] = (f32x4){bsc[s], bsc[s], bsc[s], bsc[s]};                      \
    _Pragma("unroll")                                                          \
    for (int kt = 0; kt < 4; ++kt)                                             \
        _Pragma("unroll")                                                      \
        for (int s = 0; s < 4; ++s)                                            \
            acc[s] = __builtin_amdgcn_mfma_f32_16x16x32_bf16(                  \
                af[kt], wfr[kt][s], acc[s], 0, 0, 0);                          \
    _Pragma("unroll")                                                          \
    for (int s = 0; s < 4; ++s)                                                \
        acc[s] = __builtin_amdgcn_mfma_f32_16x16x32_bf16(                      \
            hf0, ufr[0][s], acc[s], 0, 0, 0);                                  \
    _Pragma("unroll")                                                          \
    for (int s = 0; s < 4; ++s)                                                \
        acc[s] = __builtin_amdgcn_mfma_f32_16x16x32_bf16(                      \
            hf1, ufr[1][s], acc[s], 0, 0, 0);                                  \
    _Pragma("unroll")                                                          \
    for (int e = 0; e < 4; ++e) {                                              \
        float ig = sigf(acc[0][e]);                                            \
        float fg = sigf(acc[1][e]);                                            \
        float gg = tanhf_(acc[2][e]);                                          \
        float og = sigf(acc[3][e]);                                            \
        c4[e] = fmaf(fg, c4[e], ig * gg);                                      \
        hq[e] = og * tanhf_(c4[e]);                                            \
        *(short*)(hlds + (PWR) * 2048 + wr_off[e]) = f2bf(hq[e]);              \
    }                                                                          \
    __syncthreads();                                                           \
} while (0)

// Fused bidirectional LSTM via MFMA.  Block = 16 batch rows of one direction,
// 256 threads (4 waves).  Wave w owns N-tile family {w, w+4, w+8, w+12} so
// each thread's 4 accumulators are exactly (z_i, z_f, z_g, z_o) for one
// (row, j) per C-register: gates run fully in-register.  h crosses waves via
// a 4KB double-buffered LDS buffer stored directly in A-fragment layout
// (XOR-swizzled 16B slots): ONE barrier per timestep.
__global__ __launch_bounds__(256, 1)
void lstm_mfma(const float* __restrict__ x,
               const float* __restrict__ Wf, const float* __restrict__ Uf,
               const float* __restrict__ bfv,
               const float* __restrict__ Wb, const float* __restrict__ Ub,
               const float* __restrict__ bbv,
               float* __restrict__ hcat /* [B][2H] */) {
    const int tid = threadIdx.x;
    const int l = tid & 63, w = tid >> 6;
    const int lq = l >> 4, lr = l & 15;
    const int dir = blockIdx.x >> 5;
    const int r0 = (blockIdx.x & 31) * RB;

    const float* __restrict__ Wm = dir ? Wb : Wf;
    const float* __restrict__ Um = dir ? Ub : Uf;
    const float* __restrict__ bv = dir ? bbv : bfv;

    // ---- persistent B-fragments: W (4 K-tiles x 4 N-families), U (2 x 4) ----
    bf16x8 wfr[4][4];
#pragma unroll
    for (int kt = 0; kt < 4; ++kt)
#pragma unroll
        for (int s = 0; s < 4; ++s) {
            int col = (w + 4 * s) * 16 + lr;
            int k0 = kt * 32 + 4 * lq;
            bf16x8 v;
#pragma unroll
            for (int e = 0; e < 4; ++e) {
                v[e]     = f2bf(Wm[(k0 + e) * G4 + col]);
                v[e + 4] = f2bf(Wm[(k0 + 16 + e) * G4 + col]);
            }
            wfr[kt][s] = v;
        }
    bf16x8 ufr[2][4];
#pragma unroll
    for (int kt = 0; kt < 2; ++kt)
#pragma unroll
        for (int s = 0; s < 4; ++s) {
            int col = (w + 4 * s) * 16 + lr;
            int k0 = kt * 32 + 4 * lq;
            bf16x8 v;
#pragma unroll
            for (int e = 0; e < 4; ++e) {
                v[e]     = f2bf(Um[(k0 + e) * G4 + col]);
                v[e + 4] = f2bf(Um[(k0 + 16 + e) * G4 + col]);
            }
            ufr[kt][s] = v;
        }
    float bsc[4];
#pragma unroll
    for (int s = 0; s < 4; ++s) bsc[s] = bv[(w + 4 * s) * 16 + lr];

    // ---- LDS h fragment buffer (double-buffered, A-frag layout) ----
    __shared__ __align__(16) char hlds[4096];
    ((f32x4*)hlds)[tid] = (f32x4){0.f, 0.f, 0.f, 0.f};
    __syncthreads();

    // read offset: lane l's 16B frag slot (XOR swizzle keeps writes ~4-way)
    const int rd_off = (l * 16) ^ (((l >> 4) & 3) << 4);
    // write offsets: this thread produces h[row=4*lq+e][j], j = 16w + lr
    const int j = 16 * w + lr;
    const int kt_j = j >> 5;
    const int elem_j = (j & 3) + 4 * ((j >> 4) & 1);
    int wr_off[4];
#pragma unroll
    for (int e = 0; e < 4; ++e) {
        int fl = 4 * lq + e + 16 * ((j >> 2) & 3);
        wr_off[e] = kt_j * 1024 + ((fl * 16) ^ (((fl >> 4) & 3) << 4)) + elem_j * 2;
    }

    const float* xlane = x + (size_t)(r0 + lr) * (T * F);

    // prefetch t=0 and t=1
    f32x4 xrA[4][2], xrB[4][2];
    { int tt0 = dir ? (T - 1) : 0; LOADX(xrA, tt0); }
    { int tt1 = dir ? (T - 2) : 1; LOADX(xrB, tt1); }

    float c4[4] = {0.f, 0.f, 0.f, 0.f};
    float hq[4] = {0.f, 0.f, 0.f, 0.f};

    for (int t = 0; t < T; t += 2) {
        BODY(t,     xrA, 0, 1);
        BODY(t + 1, xrB, 1, 0);
    }

    // final hidden state (kept in fp32 regs, pre-rounding)
#pragma unroll
    for (int e = 0; e < 4; ++e) {
        int row = 4 * lq + e;
        hcat[(size_t)(r0 + row) * (2 * H) + dir * H + j] = hq[e];
    }
}

// out[b][e] = relu(sum_k hcat[b][k] * Wd[k][e] + bd[e])   (fp32)
__global__ void dense_kernel(const float* __restrict__ hcat,
                             const float* __restrict__ Wd,
                             const float* __restrict__ bd,
                             float* __restrict__ out) {
    const int b = blockIdx.x;
    const int e = threadIdx.x;   // 128 threads
    float acc = bd[e];
#pragma unroll
    for (int k = 0; k < 2 * H; ++k)
        acc = fmaf(hcat[b * (2 * H) + k], Wd[k * 128 + e], acc);
    out[b * 128 + e] = fmaxf(acc, 0.f);
}

extern "C" void kernel_launch(void* const* d_in, const int* in_sizes, int n_in,
                              void* d_out, int out_size, void* d_ws, size_t ws_size,
                              hipStream_t stream) {
    const float* x       = (const float*)d_in[0];
    const float* W_fwd   = (const float*)d_in[1];
    const float* U_fwd   = (const float*)d_in[2];
    const float* b_fwd   = (const float*)d_in[3];
    const float* W_bwd   = (const float*)d_in[4];
    const float* U_bwd   = (const float*)d_in[5];
    const float* b_bwd   = (const float*)d_in[6];
    const float* W_dense = (const float*)d_in[7];
    const float* b_dense = (const float*)d_in[8];
    float* out = (float*)d_out;

    float* hcat = (float*)d_ws;   // [B][2H] fp32 = 256 KB

    lstm_mfma<<<dim3(2 * (B / RB)), dim3(256), 0, stream>>>(
        x, W_fwd, U_fwd, b_fwd, W_bwd, U_bwd, b_bwd, hcat);

    dense_kernel<<<dim3(B), dim3(128), 0, stream>>>(hcat, W_dense, b_dense, out);
}

// Round 3
// 469.924 us; speedup vs baseline: 2.3332x; 1.1047x over previous
//
#include <hip/hip_runtime.h>
#include <hip/hip_bf16.h>

#define H 64
#define F 128
#define G4 256   // 4*H
#define T 512
#define B 512
#define RB 16    // batch rows per block
#define TC 8     // phase-1 time chunks per (dir,rowg)

typedef __attribute__((ext_vector_type(4))) float f32x4;
typedef __attribute__((ext_vector_type(8))) short bf16x8;

__device__ __forceinline__ short f2bf(float f) {
    union { float f; unsigned u; } v; v.f = f;
    unsigned r = (v.u + 0x7fffu + ((v.u >> 16) & 1u)) >> 16;
    return (short)r;
}
__device__ __forceinline__ float bf2f(short s) {
    union { unsigned u; float f; } v; v.u = ((unsigned)(unsigned short)s) << 16;
    return v.f;
}
__device__ __forceinline__ float sigf(float x) {
    return __builtin_amdgcn_rcpf(1.f + __expf(-x));
}
__device__ __forceinline__ float tanhf_(float x) {
    float e = __expf(2.f * x);
    return 1.f - 2.f * __builtin_amdgcn_rcpf(e + 1.f);
}

// Load one timestep's x A-fragments (4 K-tiles of 32) for this lane.
#define LOADX(XR, TT) do {                                                     \
    int _b = (TT) * F + 4 * lq;                                                \
    _Pragma("unroll")                                                          \
    for (int kt = 0; kt < 4; ++kt) {                                           \
        XR[kt][0] = *(const f32x4*)(xlane + _b + 32 * kt);                     \
        XR[kt][1] = *(const f32x4*)(xlane + _b + 32 * kt + 16);                \
    }                                                                          \
} while (0)

// ---------------------------------------------------------------------------
// Phase 1: xp[dir][rowg][t][tid][s][e] = bias + x.W  (bf16, C-frag order)
// Fully parallel over (dir, rowg, tchunk). Wave w computes N-families
// {w,w+4,w+8,w+12} so thread tid's 16 outputs are exactly what phase-2
// thread tid consumes as its accumulator init.
// ---------------------------------------------------------------------------
#define XBODY(TCUR, XR) do {                                                   \
    bf16x8 af[4];                                                              \
    _Pragma("unroll")                                                          \
    for (int kt = 0; kt < 4; ++kt) {                                           \
        bf16x8 v;                                                              \
        _Pragma("unroll")                                                      \
        for (int e = 0; e < 4; ++e) {                                          \
            v[e]     = f2bf(XR[kt][0][e]);                                     \
            v[e + 4] = f2bf(XR[kt][1][e]);                                     \
        }                                                                      \
        af[kt] = v;                                                            \
    }                                                                          \
    {   int tn = (TCUR) + 2; if (tn > T - 1) tn = T - 1;                       \
        int ttn = dir ? (T - 1 - tn) : tn;                                     \
        LOADX(XR, ttn); }                                                      \
    f32x4 acc[4];                                                              \
    _Pragma("unroll")                                                          \
    for (int s = 0; s < 4; ++s)                                                \
        acc[s] = (f32x4){bsc[s], bsc[s], bsc[s], bsc[s]};                      \
    _Pragma("unroll")                                                          \
    for (int kt = 0; kt < 4; ++kt)                                             \
        _Pragma("unroll")                                                      \
        for (int s = 0; s < 4; ++s)                                            \
            acc[s] = __builtin_amdgcn_mfma_f32_16x16x32_bf16(                  \
                af[kt], wfr[kt][s], acc[s], 0, 0, 0);                          \
    bf16x8 p0, p1;                                                             \
    _Pragma("unroll")                                                          \
    for (int e = 0; e < 4; ++e) {                                              \
        p0[e]     = f2bf(acc[0][e]);                                           \
        p0[e + 4] = f2bf(acc[1][e]);                                           \
        p1[e]     = f2bf(acc[2][e]);                                           \
        p1[e + 4] = f2bf(acc[3][e]);                                           \
    }                                                                          \
    short* dst = xp + ((size_t)(dir * 32 + rowg) * T + (TCUR)) * 4096 + tid * 16; \
    *(bf16x8*)dst = p0;                                                        \
    *(bf16x8*)(dst + 8) = p1;                                                  \
} while (0)

__global__ __launch_bounds__(256, 1)
void xw_gemm(const float* __restrict__ x,
             const float* __restrict__ Wf, const float* __restrict__ bfv,
             const float* __restrict__ Wb, const float* __restrict__ bbv,
             short* __restrict__ xp) {
    const int tid = threadIdx.x;
    const int l = tid & 63, w = tid >> 6;
    const int lq = l >> 4, lr = l & 15;
    const int dir  = blockIdx.x >> 8;
    const int rowg = (blockIdx.x >> 3) & 31;
    const int tc   = blockIdx.x & 7;
    const int r0 = rowg * RB;
    const int t0 = tc * (T / TC);

    const float* __restrict__ Wm = dir ? Wb : Wf;
    const float* __restrict__ bv = dir ? bbv : bfv;

    bf16x8 wfr[4][4];
#pragma unroll
    for (int kt = 0; kt < 4; ++kt)
#pragma unroll
        for (int s = 0; s < 4; ++s) {
            int col = (w + 4 * s) * 16 + lr;
            int k0 = kt * 32 + 4 * lq;
            bf16x8 v;
#pragma unroll
            for (int e = 0; e < 4; ++e) {
                v[e]     = f2bf(Wm[(k0 + e) * G4 + col]);
                v[e + 4] = f2bf(Wm[(k0 + 16 + e) * G4 + col]);
            }
            wfr[kt][s] = v;
        }
    float bsc[4];
#pragma unroll
    for (int s = 0; s < 4; ++s) bsc[s] = bv[(w + 4 * s) * 16 + lr];

    const float* xlane = x + (size_t)(r0 + lr) * (T * F);

    f32x4 xrA[4][2], xrB[4][2];
    { int tt0 = dir ? (T - 1 - t0) : t0;       LOADX(xrA, tt0); }
    { int tt1 = dir ? (T - 2 - t0) : (t0 + 1); LOADX(xrB, tt1); }

    for (int t = t0; t < t0 + T / TC; t += 2) {
        XBODY(t,     xrA);
        XBODY(t + 1, xrB);
    }
}

// ---------------------------------------------------------------------------
// Phase 2: recurrence only: z = xp(t) + h.U.  Serial chain per step:
// xp-cvt -> 8 MFMAs (depth 2) -> gates -> LDS h-frag exchange -> 1 barrier.
// ---------------------------------------------------------------------------
#define RBODY(TCUR, XP, PRD, PWR) do {                                         \
    f32x4 acc[4];                                                              \
    _Pragma("unroll")                                                          \
    for (int e = 0; e < 4; ++e) {                                              \
        acc[0][e] = bf2f(XP[0][e]);                                            \
        acc[1][e] = bf2f(XP[0][e + 4]);                                        \
        acc[2][e] = bf2f(XP[1][e]);                                            \
        acc[3][e] = bf2f(XP[1][e + 4]);                                        \
    }                                                                          \
    {   int tn = (TCUR) + 2; if (tn > T - 1) tn = T - 1;                       \
        const short* src = xp + ((size_t)(dir * 32 + rowg) * T + tn) * 4096    \
                           + tid * 16;                                         \
        XP[0] = *(const bf16x8*)src;                                           \
        XP[1] = *(const bf16x8*)(src + 8); }                                   \
    bf16x8 hf0 = *(const bf16x8*)(hlds + (PRD) * 2048 + rd_off);               \
    bf16x8 hf1 = *(const bf16x8*)(hlds + (PRD) * 2048 + 1024 + rd_off);        \
    _Pragma("unroll")                                                          \
    for (int s = 0; s < 4; ++s)                                                \
        acc[s] = __builtin_amdgcn_mfma_f32_16x16x32_bf16(                      \
            hf0, ufr[0][s], acc[s], 0, 0, 0);                                  \
    _Pragma("unroll")                                                          \
    for (int s = 0; s < 4; ++s)                                                \
        acc[s] = __builtin_amdgcn_mfma_f32_16x16x32_bf16(                      \
            hf1, ufr[1][s], acc[s], 0, 0, 0);                                  \
    _Pragma("unroll")                                                          \
    for (int e = 0; e < 4; ++e) {                                              \
        float ig = sigf(acc[0][e]);                                            \
        float fg = sigf(acc[1][e]);                                            \
        float gg = tanhf_(acc[2][e]);                                          \
        float og = sigf(acc[3][e]);                                            \
        c4[e] = fmaf(fg, c4[e], ig * gg);                                      \
        hq[e] = og * tanhf_(c4[e]);                                            \
        *(short*)(hlds + (PWR) * 2048 + wr_off[e]) = f2bf(hq[e]);              \
    }                                                                          \
    __syncthreads();                                                           \
} while (0)

__global__ __launch_bounds__(256, 1)
void lstm_rec(const short* __restrict__ xp,
              const float* __restrict__ Uf, const float* __restrict__ Ub,
              float* __restrict__ hcat /* [B][2H] */) {
    const int tid = threadIdx.x;
    const int l = tid & 63, w = tid >> 6;
    const int lq = l >> 4, lr = l & 15;
    const int dir = blockIdx.x >> 5;
    const int rowg = blockIdx.x & 31;
    const int r0 = rowg * RB;

    const float* __restrict__ Um = dir ? Ub : Uf;

    bf16x8 ufr[2][4];
#pragma unroll
    for (int kt = 0; kt < 2; ++kt)
#pragma unroll
        for (int s = 0; s < 4; ++s) {
            int col = (w + 4 * s) * 16 + lr;
            int k0 = kt * 32 + 4 * lq;
            bf16x8 v;
#pragma unroll
            for (int e = 0; e < 4; ++e) {
                v[e]     = f2bf(Um[(k0 + e) * G4 + col]);
                v[e + 4] = f2bf(Um[(k0 + 16 + e) * G4 + col]);
            }
            ufr[kt][s] = v;
        }

    __shared__ __align__(16) char hlds[4096];
    ((f32x4*)hlds)[tid] = (f32x4){0.f, 0.f, 0.f, 0.f};
    __syncthreads();

    const int rd_off = (l * 16) ^ (((l >> 4) & 3) << 4);
    const int j = 16 * w + lr;
    const int kt_j = j >> 5;
    const int elem_j = (j & 3) + 4 * ((j >> 4) & 1);
    int wr_off[4];
#pragma unroll
    for (int e = 0; e < 4; ++e) {
        int fl = 4 * lq + e + 16 * ((j >> 2) & 3);
        wr_off[e] = kt_j * 1024 + ((fl * 16) ^ (((fl >> 4) & 3) << 4)) + elem_j * 2;
    }

    // prefetch t=0, t=1
    bf16x8 xpA[2], xpB[2];
    {
        const short* s0 = xp + ((size_t)(dir * 32 + rowg) * T + 0) * 4096 + tid * 16;
        xpA[0] = *(const bf16x8*)s0; xpA[1] = *(const bf16x8*)(s0 + 8);
        const short* s1 = xp + ((size_t)(dir * 32 + rowg) * T + 1) * 4096 + tid * 16;
        xpB[0] = *(const bf16x8*)s1; xpB[1] = *(const bf16x8*)(s1 + 8);
    }

    float c4[4] = {0.f, 0.f, 0.f, 0.f};
    float hq[4] = {0.f, 0.f, 0.f, 0.f};

    for (int t = 0; t < T; t += 2) {
        RBODY(t,     xpA, 0, 1);
        RBODY(t + 1, xpB, 1, 0);
    }

#pragma unroll
    for (int e = 0; e < 4; ++e) {
        int row = 4 * lq + e;
        hcat[(size_t)(r0 + row) * (2 * H) + dir * H + j] = hq[e];
    }
}

// ---------------------------------------------------------------------------
// Fallback fused kernel (verified round-2 path) if ws is too small for xp.
// ---------------------------------------------------------------------------
#define BODY(TCUR, XR, PRD, PWR) do {                                          \
    bf16x8 af[4];                                                              \
    _Pragma("unroll")                                                          \
    for (int kt = 0; kt < 4; ++kt) {                                           \
        bf16x8 v;                                                              \
        _Pragma("unroll")                                                      \
        for (int e = 0; e < 4; ++e) {                                          \
            v[e]     = f2bf(XR[kt][0][e]);                                     \
            v[e + 4] = f2bf(XR[kt][1][e]);                                     \
        }                                                                      \
        af[kt] = v;                                                            \
    }                                                                          \
    {   int tn = (TCUR) + 2; if (tn > T - 1) tn = T - 1;                       \
        int ttn = dir ? (T - 1 - tn) : tn;                                     \
        LOADX(XR, ttn); }                                                      \
    bf16x8 hf0 = *(const bf16x8*)(hlds + (PRD) * 2048 + rd_off);               \
    bf16x8 hf1 = *(const bf16x8*)(hlds + (PRD) * 2048 + 1024 + rd_off);        \
    f32x4 acc[4];                                                              \
    _Pragma("unroll")                                                          \
    for (int s = 0; s < 4; ++s)                                                \
        acc[s] = (f32x4){bsc[s], bsc[s], bsc[s], bsc[s]};                      \
    _Pragma("unroll")                                                          \
    for (int kt = 0; kt < 4; ++kt)                                             \
        _Pragma("unroll")                                                      \
        for (int s = 0; s < 4; ++s)                                            \
            acc[s] = __builtin_amdgcn_mfma_f32_16x16x32_bf16(                  \
                af[kt], wfr[kt][s], acc[s], 0, 0, 0);                          \
    _Pragma("unroll")                                                          \
    for (int s = 0; s < 4; ++s)                                                \
        acc[s] = __builtin_amdgcn_mfma_f32_16x16x32_bf16(                      \
            hf0, ufr[0][s], acc[s], 0, 0, 0);                                  \
    _Pragma("unroll")                                                          \
    for (int s = 0; s < 4; ++s)                                                \
        acc[s] = __builtin_amdgcn_mfma_f32_16x16x32_bf16(                      \
            hf1, ufr[1][s], acc[s], 0, 0, 0);                                  \
    _Pragma("unroll")                                                          \
    for (int e = 0; e < 4; ++e) {                                              \
        float ig = sigf(acc[0][e]);                                            \
        float fg = sigf(acc[1][e]);                                            \
        float gg = tanhf_(acc[2][e]);                                          \
        float og = sigf(acc[3][e]);                                            \
        c4[e] = fmaf(fg, c4[e], ig * gg);                                      \
        hq[e] = og * tanhf_(c4[e]);                                            \
        *(short*)(hlds + (PWR) * 2048 + wr_off[e]) = f2bf(hq[e]);              \
    }                                                                          \
    __syncthreads();                                                           \
} while (0)

__global__ __launch_bounds__(256, 1)
void lstm_mfma(const float* __restrict__ x,
               const float* __restrict__ Wf, const float* __restrict__ Uf,
               const float* __restrict__ bfv,
               const float* __restrict__ Wb, const float* __restrict__ Ub,
               const float* __restrict__ bbv,
               float* __restrict__ hcat) {
    const int tid = threadIdx.x;
    const int l = tid & 63, w = tid >> 6;
    const int lq = l >> 4, lr = l & 15;
    const int dir = blockIdx.x >> 5;
    const int r0 = (blockIdx.x & 31) * RB;

    const float* __restrict__ Wm = dir ? Wb : Wf;
    const float* __restrict__ Um = dir ? Ub : Uf;
    const float* __restrict__ bv = dir ? bbv : bfv;

    bf16x8 wfr[4][4];
#pragma unroll
    for (int kt = 0; kt < 4; ++kt)
#pragma unroll
        for (int s = 0; s < 4; ++s) {
            int col = (w + 4 * s) * 16 + lr;
            int k0 = kt * 32 + 4 * lq;
            bf16x8 v;
#pragma unroll
            for (int e = 0; e < 4; ++e) {
                v[e]     = f2bf(Wm[(k0 + e) * G4 + col]);
                v[e + 4] = f2bf(Wm[(k0 + 16 + e) * G4 + col]);
            }
            wfr[kt][s] = v;
        }
    bf16x8 ufr[2][4];
#pragma unroll
    for (int kt = 0; kt < 2; ++kt)
#pragma unroll
        for (int s = 0; s < 4; ++s) {
            int col = (w + 4 * s) * 16 + lr;
            int k0 = kt * 32 + 4 * lq;
            bf16x8 v;
#pragma unroll
            for (int e = 0; e < 4; ++e) {
                v[e]     = f2bf(Um[(k0 + e) * G4 + col]);
                v[e + 4] = f2bf(Um[(k0 + 16 + e) * G4 + col]);
            }
            ufr[kt][s] = v;
        }
    float bsc[4];
#pragma unroll
    for (int s = 0; s < 4; ++s) bsc[s] = bv[(w + 4 * s) * 16 + lr];

    __shared__ __align__(16) char hlds[4096];
    ((f32x4*)hlds)[tid] = (f32x4){0.f, 0.f, 0.f, 0.f};
    __syncthreads();

    const int rd_off = (l * 16) ^ (((l >> 4) & 3) << 4);
    const int j = 16 * w + lr;
    const int kt_j = j >> 5;
    const int elem_j = (j & 3) + 4 * ((j >> 4) & 1);
    int wr_off[4];
#pragma unroll
    for (int e = 0; e < 4; ++e) {
        int fl = 4 * lq + e + 16 * ((j >> 2) & 3);
        wr_off[e] = kt_j * 1024 + ((fl * 16) ^ (((fl >> 4) & 3) << 4)) + elem_j * 2;
    }

    const float* xlane = x + (size_t)(r0 + lr) * (T * F);

    f32x4 xrA[4][2], xrB[4][2];
    { int tt0 = dir ? (T - 1) : 0; LOADX(xrA, tt0); }
    { int tt1 = dir ? (T - 2) : 1; LOADX(xrB, tt1); }

    float c4[4] = {0.f, 0.f, 0.f, 0.f};
    float hq[4] = {0.f, 0.f, 0.f, 0.f};

    for (int t = 0; t < T; t += 2) {
        BODY(t,     xrA, 0, 1);
        BODY(t + 1, xrB, 1, 0);
    }

#pragma unroll
    for (int e = 0; e < 4; ++e) {
        int row = 4 * lq + e;
        hcat[(size_t)(r0 + row) * (2 * H) + dir * H + j] = hq[e];
    }
}

// out[b][e] = relu(sum_k hcat[b][k] * Wd[k][e] + bd[e])   (fp32)
__global__ void dense_kernel(const float* __restrict__ hcat,
                             const float* __restrict__ Wd,
                             const float* __restrict__ bd,
                             float* __restrict__ out) {
    const int b = blockIdx.x;
    const int e = threadIdx.x;   // 128 threads
    float acc = bd[e];
#pragma unroll
    for (int k = 0; k < 2 * H; ++k)
        acc = fmaf(hcat[b * (2 * H) + k], Wd[k * 128 + e], acc);
    out[b * 128 + e] = fmaxf(acc, 0.f);
}

extern "C" void kernel_launch(void* const* d_in, const int* in_sizes, int n_in,
                              void* d_out, int out_size, void* d_ws, size_t ws_size,
                              hipStream_t stream) {
    const float* x       = (const float*)d_in[0];
    const float* W_fwd   = (const float*)d_in[1];
    const float* U_fwd   = (const float*)d_in[2];
    const float* b_fwd   = (const float*)d_in[3];
    const float* W_bwd   = (const float*)d_in[4];
    const float* U_bwd   = (const float*)d_in[5];
    const float* b_bwd   = (const float*)d_in[6];
    const float* W_dense = (const float*)d_in[7];
    const float* b_dense = (const float*)d_in[8];
    float* out = (float*)d_out;

    const size_t XP_BYTES = (size_t)2 * 32 * T * 4096 * 2;  // 268 MB (bf16)
    const size_t HCAT_BYTES = (size_t)B * 2 * H * 4;

    if (ws_size >= XP_BYTES + HCAT_BYTES) {
        short* xp   = (short*)d_ws;
        float* hcat = (float*)((char*)d_ws + XP_BYTES);

        xw_gemm<<<dim3(2 * 32 * TC), dim3(256), 0, stream>>>(
            x, W_fwd, b_fwd, W_bwd, b_bwd, xp);
        lstm_rec<<<dim3(2 * (B / RB)), dim3(256), 0, stream>>>(
            xp, U_fwd, U_bwd, hcat);
        dense_kernel<<<dim3(B), dim3(128), 0, stream>>>(hcat, W_dense, b_dense, out);
    } else {
        float* hcat = (float*)d_ws;
        lstm_mfma<<<dim3(2 * (B / RB)), dim3(256), 0, stream>>>(
            x, W_fwd, U_fwd, b_fwd, W_bwd, U_bwd, b_bwd, hcat);
        dense_kernel<<<dim3(B), dim3(128), 0, stream>>>(hcat, W_dense, b_dense, out);
    }
}

// Round 4
// 460.497 us; speedup vs baseline: 2.3809x; 1.0205x over previous
//
#include <hip/hip_runtime.h>
#include <hip/hip_bf16.h>

#define H 64
#define F 128
#define G4 256   // 4*H
#define T 512
#define B 512
#define RB 16    // batch rows per block
#define TC 8     // phase-1 time chunks per (dir,rowg)

typedef __attribute__((ext_vector_type(4))) float f32x4;
typedef __attribute__((ext_vector_type(8))) short bf16x8;

__device__ __forceinline__ short f2bf(float f) {
    union { float f; unsigned u; } v; v.f = f;
    unsigned r = (v.u + 0x7fffu + ((v.u >> 16) & 1u)) >> 16;
    return (short)r;
}
__device__ __forceinline__ float bf2f(short s) {
    union { unsigned u; float f; } v; v.u = ((unsigned)(unsigned short)s) << 16;
    return v.f;
}
__device__ __forceinline__ float sigf(float x) {
    return __builtin_amdgcn_rcpf(1.f + __expf(-x));
}
__device__ __forceinline__ float tanhf_(float x) {
    float e = __expf(2.f * x);
    return 1.f - 2.f * __builtin_amdgcn_rcpf(e + 1.f);
}

// Load one timestep's x A-fragments (4 K-tiles of 32) for this lane.
#define LOADX(XR, TT) do {                                                     \
    int _b = (TT) * F + 4 * lq;                                                \
    _Pragma("unroll")                                                          \
    for (int kt = 0; kt < 4; ++kt) {                                           \
        XR[kt][0] = *(const f32x4*)(xlane + _b + 32 * kt);                     \
        XR[kt][1] = *(const f32x4*)(xlane + _b + 32 * kt + 16);                \
    }                                                                          \
} while (0)

// ---------------------------------------------------------------------------
// Phase 1: xp[dir][rowg][t][tid][s][e] = bias + x.W  (bf16, C-frag order)
// ---------------------------------------------------------------------------
#define XBODY(TCUR, XR) do {                                                   \
    bf16x8 af[4];                                                              \
    _Pragma("unroll")                                                          \
    for (int kt = 0; kt < 4; ++kt) {                                           \
        bf16x8 v;                                                              \
        _Pragma("unroll")                                                      \
        for (int e = 0; e < 4; ++e) {                                          \
            v[e]     = f2bf(XR[kt][0][e]);                                     \
            v[e + 4] = f2bf(XR[kt][1][e]);                                     \
        }                                                                      \
        af[kt] = v;                                                            \
    }                                                                          \
    {   int tn = (TCUR) + 2; if (tn > T - 1) tn = T - 1;                       \
        int ttn = dir ? (T - 1 - tn) : tn;                                     \
        LOADX(XR, ttn); }                                                      \
    f32x4 acc[4];                                                              \
    _Pragma("unroll")                                                          \
    for (int s = 0; s < 4; ++s)                                                \
        acc[s] = (f32x4){bsc[s], bsc[s], bsc[s], bsc[s]};                      \
    _Pragma("unroll")                                                          \
    for (int kt = 0; kt < 4; ++kt)                                             \
        _Pragma("unroll")                                                      \
        for (int s = 0; s < 4; ++s)                                            \
            acc[s] = __builtin_amdgcn_mfma_f32_16x16x32_bf16(                  \
                af[kt], wfr[kt][s], acc[s], 0, 0, 0);                          \
    bf16x8 p0, p1;                                                             \
    _Pragma("unroll")                                                          \
    for (int e = 0; e < 4; ++e) {                                              \
        p0[e]     = f2bf(acc[0][e]);                                           \
        p0[e + 4] = f2bf(acc[1][e]);                                           \
        p1[e]     = f2bf(acc[2][e]);                                           \
        p1[e + 4] = f2bf(acc[3][e]);                                           \
    }                                                                          \
    short* dst = xp + ((size_t)(dir * 32 + rowg) * T + (TCUR)) * 4096 + tid * 16; \
    *(bf16x8*)dst = p0;                                                        \
    *(bf16x8*)(dst + 8) = p1;                                                  \
} while (0)

__global__ __launch_bounds__(256, 1)
void xw_gemm(const float* __restrict__ x,
             const float* __restrict__ Wf, const float* __restrict__ bfv,
             const float* __restrict__ Wb, const float* __restrict__ bbv,
             short* __restrict__ xp) {
    const int tid = threadIdx.x;
    const int l = tid & 63, w = tid >> 6;
    const int lq = l >> 4, lr = l & 15;
    const int dir  = blockIdx.x >> 8;
    const int rowg = (blockIdx.x >> 3) & 31;
    const int tc   = blockIdx.x & 7;
    const int r0 = rowg * RB;
    const int t0 = tc * (T / TC);

    const float* __restrict__ Wm = dir ? Wb : Wf;
    const float* __restrict__ bv = dir ? bbv : bfv;

    bf16x8 wfr[4][4];
#pragma unroll
    for (int kt = 0; kt < 4; ++kt)
#pragma unroll
        for (int s = 0; s < 4; ++s) {
            int col = (w + 4 * s) * 16 + lr;
            int k0 = kt * 32 + 4 * lq;
            bf16x8 v;
#pragma unroll
            for (int e = 0; e < 4; ++e) {
                v[e]     = f2bf(Wm[(k0 + e) * G4 + col]);
                v[e + 4] = f2bf(Wm[(k0 + 16 + e) * G4 + col]);
            }
            wfr[kt][s] = v;
        }
    float bsc[4];
#pragma unroll
    for (int s = 0; s < 4; ++s) bsc[s] = bv[(w + 4 * s) * 16 + lr];

    const float* xlane = x + (size_t)(r0 + lr) * (T * F);

    f32x4 xrA[4][2], xrB[4][2];
    { int tt0 = dir ? (T - 1 - t0) : t0;       LOADX(xrA, tt0); }
    { int tt1 = dir ? (T - 2 - t0) : (t0 + 1); LOADX(xrB, tt1); }

    for (int t = t0; t < t0 + T / TC; t += 2) {
        XBODY(t,     xrA);
        XBODY(t + 1, xrB);
    }
}

// ---------------------------------------------------------------------------
// Phase 2: recurrence.  Hot-loop barrier is lgkmcnt-only (raw s_barrier):
// the xp global prefetch stays in flight across barriers (no vmcnt drain),
// unlike __syncthreads() which drains vmcnt(0) every step.
// ---------------------------------------------------------------------------
#define RBODY(TCUR, XP, PRD, PWR) do {                                         \
    f32x4 acc[4];                                                              \
    _Pragma("unroll")                                                          \
    for (int e = 0; e < 4; ++e) {                                              \
        acc[0][e] = bf2f(XP[0][e]);                                            \
        acc[1][e] = bf2f(XP[0][e + 4]);                                        \
        acc[2][e] = bf2f(XP[1][e]);                                            \
        acc[3][e] = bf2f(XP[1][e + 4]);                                        \
    }                                                                          \
    {   int tn = (TCUR) + 2; if (tn > T - 1) tn = T - 1;                       \
        const short* src = xp + ((size_t)(dir * 32 + rowg) * T + tn) * 4096    \
                           + tid * 16;                                         \
        XP[0] = *(const bf16x8*)src;                                           \
        XP[1] = *(const bf16x8*)(src + 8); }                                   \
    bf16x8 hf0 = *(const bf16x8*)(hlds + (PRD) * 2048 + rd_off);               \
    bf16x8 hf1 = *(const bf16x8*)(hlds + (PRD) * 2048 + 1024 + rd_off);        \
    _Pragma("unroll")                                                          \
    for (int s = 0; s < 4; ++s)                                                \
        acc[s] = __builtin_amdgcn_mfma_f32_16x16x32_bf16(                      \
            hf0, ufr[0][s], acc[s], 0, 0, 0);                                  \
    _Pragma("unroll")                                                          \
    for (int s = 0; s < 4; ++s)                                                \
        acc[s] = __builtin_amdgcn_mfma_f32_16x16x32_bf16(                      \
            hf1, ufr[1][s], acc[s], 0, 0, 0);                                  \
    _Pragma("unroll")                                                          \
    for (int e = 0; e < 4; ++e) {                                              \
        float ig = sigf(acc[0][e]);                                            \
        float fg = sigf(acc[1][e]);                                            \
        float gg = tanhf_(acc[2][e]);                                          \
        float og = sigf(acc[3][e]);                                            \
        c4[e] = fmaf(fg, c4[e], ig * gg);                                      \
        hq[e] = og * tanhf_(c4[e]);                                            \
        *(short*)(hlds + (PWR) * 2048 + wr_off[e]) = f2bf(hq[e]);              \
    }                                                                          \
    asm volatile("s_waitcnt lgkmcnt(0)" ::: "memory");                         \
    __builtin_amdgcn_s_barrier();                                              \
    __builtin_amdgcn_sched_barrier(0);                                         \
} while (0)

__global__ __launch_bounds__(256, 1)
void lstm_rec(const short* __restrict__ xp,
              const float* __restrict__ Uf, const float* __restrict__ Ub,
              float* __restrict__ hcat /* [B][2H] */) {
    const int tid = threadIdx.x;
    const int l = tid & 63, w = tid >> 6;
    const int lq = l >> 4, lr = l & 15;
    const int dir = blockIdx.x >> 5;
    const int rowg = blockIdx.x & 31;
    const int r0 = rowg * RB;

    const float* __restrict__ Um = dir ? Ub : Uf;

    bf16x8 ufr[2][4];
#pragma unroll
    for (int kt = 0; kt < 2; ++kt)
#pragma unroll
        for (int s = 0; s < 4; ++s) {
            int col = (w + 4 * s) * 16 + lr;
            int k0 = kt * 32 + 4 * lq;
            bf16x8 v;
#pragma unroll
            for (int e = 0; e < 4; ++e) {
                v[e]     = f2bf(Um[(k0 + e) * G4 + col]);
                v[e + 4] = f2bf(Um[(k0 + 16 + e) * G4 + col]);
            }
            ufr[kt][s] = v;
        }

    __shared__ __align__(16) char hlds[4096];
    ((f32x4*)hlds)[tid] = (f32x4){0.f, 0.f, 0.f, 0.f};
    __syncthreads();

    const int rd_off = (l * 16) ^ (((l >> 4) & 3) << 4);
    const int j = 16 * w + lr;
    const int kt_j = j >> 5;
    const int elem_j = (j & 3) + 4 * ((j >> 4) & 1);
    int wr_off[4];
#pragma unroll
    for (int e = 0; e < 4; ++e) {
        int fl = 4 * lq + e + 16 * ((j >> 2) & 3);
        wr_off[e] = kt_j * 1024 + ((fl * 16) ^ (((fl >> 4) & 3) << 4)) + elem_j * 2;
    }

    // prefetch t=0, t=1
    bf16x8 xpA[2], xpB[2];
    {
        const short* s0 = xp + ((size_t)(dir * 32 + rowg) * T + 0) * 4096 + tid * 16;
        xpA[0] = *(const bf16x8*)s0; xpA[1] = *(const bf16x8*)(s0 + 8);
        const short* s1 = xp + ((size_t)(dir * 32 + rowg) * T + 1) * 4096 + tid * 16;
        xpB[0] = *(const bf16x8*)s1; xpB[1] = *(const bf16x8*)(s1 + 8);
    }

    float c4[4] = {0.f, 0.f, 0.f, 0.f};
    float hq[4] = {0.f, 0.f, 0.f, 0.f};

    for (int t = 0; t < T; t += 2) {
        RBODY(t,     xpA, 0, 1);
        RBODY(t + 1, xpB, 1, 0);
    }

#pragma unroll
    for (int e = 0; e < 4; ++e) {
        int row = 4 * lq + e;
        hcat[(size_t)(r0 + row) * (2 * H) + dir * H + j] = hq[e];
    }
}

// ---------------------------------------------------------------------------
// Fallback fused kernel (verified round-2 path) if ws is too small for xp.
// ---------------------------------------------------------------------------
#define BODY(TCUR, XR, PRD, PWR) do {                                          \
    bf16x8 af[4];                                                              \
    _Pragma("unroll")                                                          \
    for (int kt = 0; kt < 4; ++kt) {                                           \
        bf16x8 v;                                                              \
        _Pragma("unroll")                                                      \
        for (int e = 0; e < 4; ++e) {                                          \
            v[e]     = f2bf(XR[kt][0][e]);                                     \
            v[e + 4] = f2bf(XR[kt][1][e]);                                     \
        }                                                                      \
        af[kt] = v;                                                            \
    }                                                                          \
    {   int tn = (TCUR) + 2; if (tn > T - 1) tn = T - 1;                       \
        int ttn = dir ? (T - 1 - tn) : tn;                                     \
        LOADX(XR, ttn); }                                                      \
    bf16x8 hf0 = *(const bf16x8*)(hlds + (PRD) * 2048 + rd_off);               \
    bf16x8 hf1 = *(const bf16x8*)(hlds + (PRD) * 2048 + 1024 + rd_off);        \
    f32x4 acc[4];                                                              \
    _Pragma("unroll")                                                          \
    for (int s = 0; s < 4; ++s)                                                \
        acc[s] = (f32x4){bsc[s], bsc[s], bsc[s], bsc[s]};                      \
    _Pragma("unroll")                                                          \
    for (int kt = 0; kt < 4; ++kt)                                             \
        _Pragma("unroll")                                                      \
        for (int s = 0; s < 4; ++s)                                            \
            acc[s] = __builtin_amdgcn_mfma_f32_16x16x32_bf16(                  \
                af[kt], wfr[kt][s], acc[s], 0, 0, 0);                          \
    _Pragma("unroll")                                                          \
    for (int s = 0; s < 4; ++s)                                                \
        acc[s] = __builtin_amdgcn_mfma_f32_16x16x32_bf16(                      \
            hf0, ufr[0][s], acc[s], 0, 0, 0);                                  \
    _Pragma("unroll")                                                          \
    for (int s = 0; s < 4; ++s)                                                \
        acc[s] = __builtin_amdgcn_mfma_f32_16x16x32_bf16(                      \
            hf1, ufr[1][s], acc[s], 0, 0, 0);                                  \
    _Pragma("unroll")                                                          \
    for (int e = 0; e < 4; ++e) {                                              \
        float ig = sigf(acc[0][e]);                                            \
        float fg = sigf(acc[1][e]);                                            \
        float gg = tanhf_(acc[2][e]);                                          \
        float og = sigf(acc[3][e]);                                            \
        c4[e] = fmaf(fg, c4[e], ig * gg);                                      \
        hq[e] = og * tanhf_(c4[e]);                                            \
        *(short*)(hlds + (PWR) * 2048 + wr_off[e]) = f2bf(hq[e]);              \
    }                                                                          \
    __syncthreads();                                                           \
} while (0)

__global__ __launch_bounds__(256, 1)
void lstm_mfma(const float* __restrict__ x,
               const float* __restrict__ Wf, const float* __restrict__ Uf,
               const float* __restrict__ bfv,
               const float* __restrict__ Wb, const float* __restrict__ Ub,
               const float* __restrict__ bbv,
               float* __restrict__ hcat) {
    const int tid = threadIdx.x;
    const int l = tid & 63, w = tid >> 6;
    const int lq = l >> 4, lr = l & 15;
    const int dir = blockIdx.x >> 5;
    const int r0 = (blockIdx.x & 31) * RB;

    const float* __restrict__ Wm = dir ? Wb : Wf;
    const float* __restrict__ Um = dir ? Ub : Uf;
    const float* __restrict__ bv = dir ? bbv : bfv;

    bf16x8 wfr[4][4];
#pragma unroll
    for (int kt = 0; kt < 4; ++kt)
#pragma unroll
        for (int s = 0; s < 4; ++s) {
            int col = (w + 4 * s) * 16 + lr;
            int k0 = kt * 32 + 4 * lq;
            bf16x8 v;
#pragma unroll
            for (int e = 0; e < 4; ++e) {
                v[e]     = f2bf(Wm[(k0 + e) * G4 + col]);
                v[e + 4] = f2bf(Wm[(k0 + 16 + e) * G4 + col]);
            }
            wfr[kt][s] = v;
        }
    bf16x8 ufr[2][4];
#pragma unroll
    for (int kt = 0; kt < 2; ++kt)
#pragma unroll
        for (int s = 0; s < 4; ++s) {
            int col = (w + 4 * s) * 16 + lr;
            int k0 = kt * 32 + 4 * lq;
            bf16x8 v;
#pragma unroll
            for (int e = 0; e < 4; ++e) {
                v[e]     = f2bf(Um[(k0 + e) * G4 + col]);
                v[e + 4] = f2bf(Um[(k0 + 16 + e) * G4 + col]);
            }
            ufr[kt][s] = v;
        }
    float bsc[4];
#pragma unroll
    for (int s = 0; s < 4; ++s) bsc[s] = bv[(w + 4 * s) * 16 + lr];

    __shared__ __align__(16) char hlds[4096];
    ((f32x4*)hlds)[tid] = (f32x4){0.f, 0.f, 0.f, 0.f};
    __syncthreads();

    const int rd_off = (l * 16) ^ (((l >> 4) & 3) << 4);
    const int j = 16 * w + lr;
    const int kt_j = j >> 5;
    const int elem_j = (j & 3) + 4 * ((j >> 4) & 1);
    int wr_off[4];
#pragma unroll
    for (int e = 0; e < 4; ++e) {
        int fl = 4 * lq + e + 16 * ((j >> 2) & 3);
        wr_off[e] = kt_j * 1024 + ((fl * 16) ^ (((fl >> 4) & 3) << 4)) + elem_j * 2;
    }

    const float* xlane = x + (size_t)(r0 + lr) * (T * F);

    f32x4 xrA[4][2], xrB[4][2];
    { int tt0 = dir ? (T - 1) : 0; LOADX(xrA, tt0); }
    { int tt1 = dir ? (T - 2) : 1; LOADX(xrB, tt1); }

    float c4[4] = {0.f, 0.f, 0.f, 0.f};
    float hq[4] = {0.f, 0.f, 0.f, 0.f};

    for (int t = 0; t < T; t += 2) {
        BODY(t,     xrA, 0, 1);
        BODY(t + 1, xrB, 1, 0);
    }

#pragma unroll
    for (int e = 0; e < 4; ++e) {
        int row = 4 * lq + e;
        hcat[(size_t)(r0 + row) * (2 * H) + dir * H + j] = hq[e];
    }
}

// out[b][e] = relu(sum_k hcat[b][k] * Wd[k][e] + bd[e])   (fp32)
__global__ void dense_kernel(const float* __restrict__ hcat,
                             const float* __restrict__ Wd,
                             const float* __restrict__ bd,
                             float* __restrict__ out) {
    const int b = blockIdx.x;
    const int e = threadIdx.x;   // 128 threads
    float acc = bd[e];
#pragma unroll
    for (int k = 0; k < 2 * H; ++k)
        acc = fmaf(hcat[b * (2 * H) + k], Wd[k * 128 + e], acc);
    out[b * 128 + e] = fmaxf(acc, 0.f);
}

extern "C" void kernel_launch(void* const* d_in, const int* in_sizes, int n_in,
                              void* d_out, int out_size, void* d_ws, size_t ws_size,
                              hipStream_t stream) {
    const float* x       = (const float*)d_in[0];
    const float* W_fwd   = (const float*)d_in[1];
    const float* U_fwd   = (const float*)d_in[2];
    const float* b_fwd   = (const float*)d_in[3];
    const float* W_bwd   = (const float*)d_in[4];
    const float* U_bwd   = (const float*)d_in[5];
    const float* b_bwd   = (const float*)d_in[6];
    const float* W_dense = (const float*)d_in[7];
    const float* b_dense = (const float*)d_in[8];
    float* out = (float*)d_out;

    const size_t XP_BYTES = (size_t)2 * 32 * T * 4096 * 2;  // 268 MB (bf16)
    const size_t HCAT_BYTES = (size_t)B * 2 * H * 4;

    if (ws_size >= XP_BYTES + HCAT_BYTES) {
        short* xp   = (short*)d_ws;
        float* hcat = (float*)((char*)d_ws + XP_BYTES);

        xw_gemm<<<dim3(2 * 32 * TC), dim3(256), 0, stream>>>(
            x, W_fwd, b_fwd, W_bwd, b_bwd, xp);
        lstm_rec<<<dim3(2 * (B / RB)), dim3(256), 0, stream>>>(
            xp, U_fwd, U_bwd, hcat);
        dense_kernel<<<dim3(B), dim3(128), 0, stream>>>(hcat, W_dense, b_dense, out);
    } else {
        float* hcat = (float*)d_ws;
        lstm_mfma<<<dim3(2 * (B / RB)), dim3(256), 0, stream>>>(
            x, W_fwd, U_fwd, b_fwd, W_bwd, U_bwd, b_bwd, hcat);
        dense_kernel<<<dim3(B), dim3(128), 0, stream>>>(hcat, W_dense, b_dense, out);
    }
}